// Round 2
// baseline (752.184 us; speedup 1.0000x reference)
//
#include <hip/hip_runtime.h>

#define NWIN 4096
#define KTOK 32
#define CH 256
#define NH 8
#define NTOK (NWIN*KTOK)

typedef unsigned short bf16u;
typedef __attribute__((ext_vector_type(4))) float f32x4;
typedef __attribute__((ext_vector_type(4))) unsigned short u16x4;
typedef __attribute__((ext_vector_type(8))) unsigned short u16x8;
typedef __attribute__((ext_vector_type(8))) __bf16 bf16x8;

__device__ __forceinline__ unsigned short f2bf(float f) {
  unsigned u = __builtin_bit_cast(unsigned, f);
  u += 0x7fffu + ((u >> 16) & 1u);
  return (unsigned short)(u >> 16);
}

__device__ __forceinline__ f32x4 mfma16(bf16x8 a, bf16x8 b, f32x4 c) {
  return __builtin_amdgcn_mfma_f32_16x16x32_bf16(a, b, c, 0, 0, 0);
}

__device__ __forceinline__ float gelu_f(float x) {
  float u = x + 0.044715f * x * x * x;
  return x / (1.f + __expf(-1.5957691216057308f * u));
}

// ---- weight prep: W (K x N) f32 -> Wt (N x K) bf16 ----
__global__ __launch_bounds__(256) void wprep_kernel(const float* __restrict__ W,
                                                    bf16u* __restrict__ Wt,
                                                    int Kd, int Nd) {
  int idx = blockIdx.x * 256 + threadIdx.x;
  if (idx >= Kd * Nd) return;
  int k = idx / Nd, n = idx - k * Nd;
  Wt[n * Kd + k] = f2bf(W[idx]);
}

// ---- LayerNorm: one wave per 256-col row, f32 in -> bf16 out ----
__global__ __launch_bounds__(256) void ln_kernel(const float* __restrict__ x,
                                                 const float* __restrict__ g,
                                                 const float* __restrict__ b,
                                                 bf16u* __restrict__ y) {
  const int row = blockIdx.x * 4 + (threadIdx.x >> 6);
  const int lane = threadIdx.x & 63;
  const size_t base = (size_t)row * CH + lane * 4;
  const f32x4 v = *(const f32x4*)(x + base);
  float s = v[0] + v[1] + v[2] + v[3];
  float q = v[0]*v[0] + v[1]*v[1] + v[2]*v[2] + v[3]*v[3];
  #pragma unroll
  for (int d = 32; d; d >>= 1) { s += __shfl_xor(s, d); q += __shfl_xor(q, d); }
  const float mean = s * (1.f/256.f);
  const float rs = rsqrtf(q * (1.f/256.f) - mean*mean + 1e-5f);
  const f32x4 gv = *(const f32x4*)(g + lane*4);
  const f32x4 bv = *(const f32x4*)(b + lane*4);
  u16x4 o;
  #pragma unroll
  for (int d = 0; d < 4; ++d) o[d] = f2bf((v[d]-mean)*rs*gv[d] + bv[d]);
  *(u16x4*)(y + base) = o;
}

// ---- 128x128 MFMA GEMM (diagnostic-simple staging + direct epilogue) ----
// EPI 0: +bias -> bf16 ; EPI 1: +bias,gelu -> bf16 ; EPI 2: +bias+resid -> f32
template<int EPI>
__global__ __launch_bounds__(256, 2)
void gemm_kernel(const bf16u* __restrict__ A, const bf16u* __restrict__ Bt,
                 const float* __restrict__ bias, const float* __restrict__ resid,
                 void* __restrict__ out, int M, int N, int K) {
  __shared__ __align__(16) char lds[16384];
  const int tid = threadIdx.x;
  const int lane = tid & 63;
  const int wv = tid >> 6;
  const int lo = lane & 15, hi = lane >> 4;
  const int bm = blockIdx.y * 128, bn = blockIdx.x * 128;
  const int wm = (wv >> 1) * 64, wn = (wv & 1) * 64;
  char* As = lds;
  char* Bs = lds + 8192;

  f32x4 acc[4][4] = {};

  for (int k0 = 0; k0 < K; k0 += 32) {
    __syncthreads();
    // stage A,B tiles: 128 rows x 32 k each; 512 chunks of 8 bf16 per tile
    #pragma unroll
    for (int t = 0; t < 2; ++t) {
      const int c = tid + t*256;          // 0..511
      const int row = c >> 2;             // 0..127
      const int ck = (c & 3) * 8;         // k sub-offset (elements)
      u16x8 va = *(const u16x8*)(A + (size_t)(bm + row) * K + k0 + ck);
      u16x8 vb = *(const u16x8*)(Bt + (size_t)(bn + row) * K + k0 + ck);
      *(u16x8*)(As + row*64 + ck*2) = va;
      *(u16x8*)(Bs + row*64 + ck*2) = vb;
    }
    __syncthreads();
    bf16x8 af[4], bfv[4];
    #pragma unroll
    for (int i = 0; i < 4; ++i) {
      af[i]  = *(const bf16x8*)(As + (wm + i*16 + lo)*64 + hi*16);
      bfv[i] = *(const bf16x8*)(Bs + (wn + i*16 + lo)*64 + hi*16);
    }
    #pragma unroll
    for (int i = 0; i < 4; ++i)
      #pragma unroll
      for (int j = 0; j < 4; ++j)
        acc[i][j] = mfma16(af[i], bfv[j], acc[i][j]);
  }

  // direct epilogue from the m89 D-layout: row = hi*4+r, col = lo
  const int mb = bm + wm, nb = bn + wn;
  #pragma unroll
  for (int i = 0; i < 4; ++i) {
    #pragma unroll
    for (int j = 0; j < 4; ++j) {
      const int n = nb + j*16 + lo;
      const float bv = bias[n];
      #pragma unroll
      for (int r = 0; r < 4; ++r) {
        const int m = mb + i*16 + hi*4 + r;
        float v = acc[i][j][r] + bv;
        if constexpr (EPI == 2) {
          v += resid[(size_t)m*N + n];
          ((float*)out)[(size_t)m*N + n] = v;
        } else {
          if constexpr (EPI == 1) v = gelu_f(v);
          ((bf16u*)out)[(size_t)m*N + n] = f2bf(v);
        }
      }
    }
  }
}

// ---- fused window attention: one block per window, 2 heads per wave ----
__global__ __launch_bounds__(256, 2)
void attn_kernel(const bf16u* __restrict__ qkv, const float* __restrict__ mask,
                 const int* __restrict__ relp, const float* __restrict__ rpe,
                 bf16u* __restrict__ outp) {
  const int w = blockIdx.x;
  const int tid = threadIdx.x, lane = tid & 63, wv = tid >> 6;
  const int lo = lane & 15, hi = lane >> 4;

  __shared__ __align__(16) bf16u sQK[32*520];      // [tok][q(256)|k(256)|pad(8)]
  __shared__ __align__(16) bf16u sVT[8][32][40];   // V^T per head, +8 pad
  __shared__ __align__(16) bf16u sP[4][32][40];    // per-wave P
  __shared__ float sTab[1232];
  __shared__ int sRel[1024];
  __shared__ float sMask[1024];

  const size_t qbase = (size_t)w * (32*768);
  {
    #pragma unroll
    for (int t = 0; t < 8; ++t) {          // stage Q,K rows (1024 B data + 16 B pad)
      int i = tid + t*256;
      int tok = i >> 6;
      int cb = (i & 63) * 16;              // 0..1008
      *(u16x8*)((char*)sQK + tok*1040 + cb) =
          *(const u16x8*)((const char*)(qkv + qbase) + tok*1536 + cb);
    }
    #pragma unroll
    for (int t = 0; t < 4; ++t) {          // stage V transposed
      int i = tid + t*256;
      int tok = i >> 5, c8 = i & 31;
      int h = c8 >> 2, d0 = (c8 & 3) * 8;
      u16x8 v8 = *(const u16x8*)(qkv + qbase + tok*768 + 512 + c8*8);
      #pragma unroll
      for (int j = 0; j < 8; ++j) sVT[h][d0 + j][tok] = v8[j];
    }
    for (int i = tid; i < 1224; i += 256) sTab[i] = rpe[i];
    #pragma unroll
    for (int t = 0; t < 4; ++t) {          // pack clipped RPE indices
      int i = tid + t*256;
      const int* rp = relp + ((size_t)w*1024 + i)*3;
      int r0 = rp[0], r1 = rp[1], r2 = rp[2];
      r0 = min(max(r0, -25), 25) + 25;
      r1 = min(max(r1, -25), 25) + 76;
      r2 = min(max(r2, -25), 25) + 127;
      sRel[i] = r0 | (r1 << 8) | (r2 << 16);
    }
    *(f32x4*)(sMask + tid*4) = *(const f32x4*)(mask + (size_t)w*1024 + tid*4);
  }
  __syncthreads();

  const float scale = 0.17677669529663687f;  // 1/sqrt(32)
  #pragma unroll
  for (int e = 0; e < 2; ++e) {
    const int h = wv*2 + e;
    bf16x8 qf[2], kf[2];
    #pragma unroll
    for (int rf = 0; rf < 2; ++rf) {
      int tok = rf*16 + lo;
      qf[rf] = *(const bf16x8*)((const char*)sQK + tok*1040 + h*64 + hi*16);
      kf[rf] = *(const bf16x8*)((const char*)sQK + tok*1040 + 512 + h*64 + hi*16);
    }
    f32x4 S[2][2] = {};
    #pragma unroll
    for (int rf = 0; rf < 2; ++rf)
      #pragma unroll
      for (int cf = 0; cf < 2; ++cf)
        S[rf][cf] = mfma16(qf[rf], kf[cf], S[rf][cf]);
    // scale + RPE bias + mask
    #pragma unroll
    for (int rf = 0; rf < 2; ++rf)
      #pragma unroll
      for (int cf = 0; cf < 2; ++cf)
        #pragma unroll
        for (int r = 0; r < 4; ++r) {
          const int qq = rf*16 + hi*4 + r;
          const int kk = cf*16 + lo;
          const int pk = sRel[qq*32 + kk];
          const float bsum = sTab[(pk & 255)*8 + h] + sTab[((pk >> 8) & 255)*8 + h]
                           + sTab[((pk >> 16) & 255)*8 + h];
          S[rf][cf][r] = S[rf][cf][r] * scale + bsum + sMask[qq*32 + kk];
        }
    // row softmax over (cf, lo)
    #pragma unroll
    for (int rf = 0; rf < 2; ++rf)
      #pragma unroll
      for (int r = 0; r < 4; ++r) {
        float m0 = fmaxf(S[rf][0][r], S[rf][1][r]);
        #pragma unroll
        for (int d = 1; d < 16; d <<= 1) m0 = fmaxf(m0, __shfl_xor(m0, d));
        const float p0 = __expf(S[rf][0][r] - m0);
        const float p1 = __expf(S[rf][1][r] - m0);
        float ss = p0 + p1;
        #pragma unroll
        for (int d = 1; d < 16; d <<= 1) ss += __shfl_xor(ss, d);
        const float inv = 1.f / ss;
        S[rf][0][r] = p0 * inv;
        S[rf][1][r] = p1 * inv;
      }
    // P -> LDS (A-frag layout), then PV
    #pragma unroll
    for (int rf = 0; rf < 2; ++rf)
      #pragma unroll
      for (int cf = 0; cf < 2; ++cf)
        #pragma unroll
        for (int r = 0; r < 4; ++r)
          sP[wv][rf*16 + hi*4 + r][cf*16 + lo] = f2bf(S[rf][cf][r]);
    bf16x8 pf[2], vf[2];
    #pragma unroll
    for (int rf = 0; rf < 2; ++rf) {
      pf[rf] = *(const bf16x8*)&sP[wv][rf*16 + lo][hi*8];
      vf[rf] = *(const bf16x8*)&sVT[h][rf*16 + lo][hi*8];
    }
    f32x4 O[2][2] = {};
    #pragma unroll
    for (int rf = 0; rf < 2; ++rf)
      #pragma unroll
      for (int cf = 0; cf < 2; ++cf)
        O[rf][cf] = mfma16(pf[rf], vf[cf], O[rf][cf]);
    #pragma unroll
    for (int rf = 0; rf < 2; ++rf)
      #pragma unroll
      for (int cf = 0; cf < 2; ++cf)
        #pragma unroll
        for (int r = 0; r < 4; ++r) {
          const int qq = rf*16 + hi*4 + r;
          outp[(size_t)(w*32 + qq)*256 + h*32 + cf*16 + lo] = f2bf(O[rf][cf][r]);
        }
  }
}

extern "C" void kernel_launch(void* const* d_in, const int* in_sizes, int n_in,
                              void* d_out, int out_size, void* d_ws, size_t ws_size,
                              hipStream_t stream) {
  const float* data   = (const float*)d_in[0];
  const float* mask   = (const float*)d_in[1];
  const int*   relp   = (const int*)d_in[2];
  const float* qkv_w  = (const float*)d_in[3];
  const float* qkv_b  = (const float*)d_in[4];
  const float* proj_w = (const float*)d_in[5];
  const float* proj_b = (const float*)d_in[6];
  const float* rpe    = (const float*)d_in[7];
  const float* ln1_g  = (const float*)d_in[8];
  const float* ln1_b  = (const float*)d_in[9];
  const float* ln2_g  = (const float*)d_in[10];
  const float* ln2_b  = (const float*)d_in[11];
  const float* fc1_w  = (const float*)d_in[12];
  const float* fc1_b  = (const float*)d_in[13];
  const float* fc2_w  = (const float*)d_in[14];
  const float* fc2_b  = (const float*)d_in[15];

  char* ws = (char*)d_ws;
  bf16u* wt_qkv  = (bf16u*)(ws);                 // 768x256
  bf16u* wt_proj = (bf16u*)(ws + 393216);        // 256x256
  bf16u* wt_fc1  = (bf16u*)(ws + 524288);        // 1024x256
  bf16u* wt_fc2  = (bf16u*)(ws + 1048576);       // 256x1024
  bf16u* xbuf    = (bf16u*)(ws + 2097152);                  // 131072x256
  bf16u* qkvbuf  = (bf16u*)(ws + 2097152 + 67108864);       // 131072x768 / x1024
  float* data2   = (float*)d_out;                // residual stream lives in d_out

  wprep_kernel<<<768, 256, 0, stream>>>(qkv_w, wt_qkv, 256, 768);
  wprep_kernel<<<256, 256, 0, stream>>>(proj_w, wt_proj, 256, 256);
  wprep_kernel<<<1024, 256, 0, stream>>>(fc1_w, wt_fc1, 256, 1024);
  wprep_kernel<<<1024, 256, 0, stream>>>(fc2_w, wt_fc2, 1024, 256);

  ln_kernel<<<32768, 256, 0, stream>>>(data, ln1_g, ln1_b, xbuf);
  gemm_kernel<0><<<dim3(6, 1024), 256, 0, stream>>>(xbuf, wt_qkv, qkv_b, nullptr,
                                                    qkvbuf, NTOK, 768, 256);
  attn_kernel<<<NWIN, 256, 0, stream>>>(qkvbuf, mask, relp, rpe, xbuf);
  gemm_kernel<2><<<dim3(2, 1024), 256, 0, stream>>>(xbuf, wt_proj, proj_b, data,
                                                    data2, NTOK, 256, 256);
  ln_kernel<<<32768, 256, 0, stream>>>(data2, ln2_g, ln2_b, xbuf);
  gemm_kernel<1><<<dim3(8, 1024), 256, 0, stream>>>(xbuf, wt_fc1, fc1_b, nullptr,
                                                    qkvbuf, NTOK, 1024, 256);
  gemm_kernel<2><<<dim3(2, 1024), 256, 0, stream>>>(qkvbuf, wt_fc2, fc2_b, data2,
                                                    d_out, NTOK, 256, 1024);
}

// Round 3
// 668.379 us; speedup vs baseline: 1.1254x; 1.1254x over previous
//
#include <hip/hip_runtime.h>

#define NWIN 4096
#define KTOK 32
#define CH 256
#define NH 8
#define NTOK (NWIN*KTOK)

typedef unsigned short bf16u;
typedef __attribute__((ext_vector_type(4))) float f32x4;
typedef __attribute__((ext_vector_type(4))) unsigned short u16x4;
typedef __attribute__((ext_vector_type(8))) unsigned short u16x8;
typedef __attribute__((ext_vector_type(8))) __bf16 bf16x8;

__device__ __forceinline__ unsigned short f2bf(float f) {
  unsigned u = __builtin_bit_cast(unsigned, f);
  u += 0x7fffu + ((u >> 16) & 1u);
  return (unsigned short)(u >> 16);
}

__device__ __forceinline__ f32x4 mfma16(bf16x8 a, bf16x8 b, f32x4 c) {
  return __builtin_amdgcn_mfma_f32_16x16x32_bf16(a, b, c, 0, 0, 0);
}

__device__ __forceinline__ void gl16(const void* g, void* l) {
  __builtin_amdgcn_global_load_lds(
      (const __attribute__((address_space(1))) unsigned int*)g,
      (__attribute__((address_space(3))) unsigned int*)l, 16, 0, 0);
}

__device__ __forceinline__ float gelu_f(float x) {
  float u = x + 0.044715f * x * x * x;
  return x / (1.f + __expf(-1.5957691216057308f * u));
}

// ---- weight prep: W (K x N) f32 -> Wt (N x K) bf16 ----
__global__ __launch_bounds__(256) void wprep_kernel(const float* __restrict__ W,
                                                    bf16u* __restrict__ Wt,
                                                    int Kd, int Nd) {
  int idx = blockIdx.x * 256 + threadIdx.x;
  if (idx >= Kd * Nd) return;
  int k = idx / Nd, n = idx - k * Nd;
  Wt[n * Kd + k] = f2bf(W[idx]);
}

// ---- LayerNorm: one wave per 256-col row, f32 in -> bf16 out ----
__global__ __launch_bounds__(256) void ln_kernel(const float* __restrict__ x,
                                                 const float* __restrict__ g,
                                                 const float* __restrict__ b,
                                                 bf16u* __restrict__ y) {
  const int row = blockIdx.x * 4 + (threadIdx.x >> 6);
  const int lane = threadIdx.x & 63;
  const size_t base = (size_t)row * CH + lane * 4;
  const f32x4 v = *(const f32x4*)(x + base);
  float s = v[0] + v[1] + v[2] + v[3];
  float q = v[0]*v[0] + v[1]*v[1] + v[2]*v[2] + v[3]*v[3];
  #pragma unroll
  for (int d = 32; d; d >>= 1) { s += __shfl_xor(s, d); q += __shfl_xor(q, d); }
  const float mean = s * (1.f/256.f);
  const float rs = rsqrtf(q * (1.f/256.f) - mean*mean + 1e-5f);
  const f32x4 gv = *(const f32x4*)(g + lane*4);
  const f32x4 bv = *(const f32x4*)(b + lane*4);
  u16x4 o;
  #pragma unroll
  for (int d = 0; d < 4; ++d) o[d] = f2bf((v[d]-mean)*rs*gv[d] + bv[d]);
  *(u16x4*)(y + base) = o;
}

// ---- 128x128 MFMA GEMM: gl16 staging + direct epilogue + XCD swizzle ----
// EPI 0: +bias -> bf16 ; EPI 1: +bias,gelu -> bf16 ; EPI 2: +bias+resid -> f32
template<int EPI>
__global__ __launch_bounds__(256, 2)
void gemm_kernel(const bf16u* __restrict__ A, const bf16u* __restrict__ Bt,
                 const float* __restrict__ bias, const float* __restrict__ resid,
                 void* __restrict__ out, int M, int N, int K, int nx) {
  __shared__ __align__(16) char lds[16384];
  const int tid = threadIdx.x;
  const int lane = tid & 63;
  const int wv = tid >> 6;
  const int lo = lane & 15, hi = lane >> 4;
  // T1 bijective XCD swizzle (nwg divisible by 8); bx fast within chunk so
  // n-tiles sharing an A-panel stay on one XCD's L2.
  const int nwg = gridDim.x;
  const int cpx = nwg >> 3;
  const int swz = (blockIdx.x & 7) * cpx + (blockIdx.x >> 3);
  const int by = swz / nx, bx = swz - by * nx;
  const int bm = by * 128, bn = bx * 128;
  const int wm = (wv >> 1) * 64, wn = (wv & 1) * 64;
  char* As = lds;
  char* Bs = lds + 8192;

  f32x4 acc[4][4] = {};

  const int srow = tid >> 2;          // 0..63
  const int sk = (tid & 3) * 16;      // byte offset inside 64B k-row
  const size_t rstep = (size_t)64 * K * 2;  // bytes for 64 rows
  const char* gA = (const char*)(A + (size_t)(bm + srow) * K) + sk;
  const char* gB = (const char*)(Bt + (size_t)(bn + srow) * K) + sk;

  for (int k0 = 0; k0 < K; k0 += 32) {
    __syncthreads();
    const char* ga = gA + k0 * 2;
    const char* gb = gB + k0 * 2;
    gl16(ga,         As + tid*16);
    gl16(ga + rstep, As + 4096 + tid*16);
    gl16(gb,         Bs + tid*16);
    gl16(gb + rstep, Bs + 4096 + tid*16);
    __syncthreads();
    bf16x8 af[4], bfv[4];
    #pragma unroll
    for (int i = 0; i < 4; ++i) {
      af[i]  = *(const bf16x8*)(As + (wm + i*16 + lo)*64 + hi*16);
      bfv[i] = *(const bf16x8*)(Bs + (wn + i*16 + lo)*64 + hi*16);
    }
    #pragma unroll
    for (int i = 0; i < 4; ++i)
      #pragma unroll
      for (int j = 0; j < 4; ++j)
        acc[i][j] = mfma16(af[i], bfv[j], acc[i][j]);
  }

  // direct epilogue from the m89 D-layout: row = hi*4+r, col = lo
  const int mb = bm + wm, nb = bn + wn;
  #pragma unroll
  for (int i = 0; i < 4; ++i) {
    #pragma unroll
    for (int j = 0; j < 4; ++j) {
      const int n = nb + j*16 + lo;
      const float bv = bias[n];
      #pragma unroll
      for (int r = 0; r < 4; ++r) {
        const int m = mb + i*16 + hi*4 + r;
        float v = acc[i][j][r] + bv;
        if constexpr (EPI == 2) {
          v += resid[(size_t)m*N + n];
          ((float*)out)[(size_t)m*N + n] = v;
        } else {
          if constexpr (EPI == 1) v = gelu_f(v);
          ((bf16u*)out)[(size_t)m*N + n] = f2bf(v);
        }
      }
    }
  }
}

// ---- fused window attention: one block per window, 2 heads per wave ----
__global__ __launch_bounds__(256, 2)
void attn_kernel(const bf16u* __restrict__ qkv, const float* __restrict__ mask,
                 const int* __restrict__ relp, const float* __restrict__ rpe,
                 bf16u* __restrict__ outp) {
  const int w = blockIdx.x;
  const int tid = threadIdx.x, lane = tid & 63, wv = tid >> 6;
  const int lo = lane & 15, hi = lane >> 4;

  __shared__ __align__(16) bf16u sQK[32*520];     // [tok][q(256)|k(256)|pad]
  __shared__ __align__(16) bf16u sV[32][264];     // V rows, row-major, pad 8
  __shared__ __align__(16) bf16u sP[4][32][44];   // per-wave P, pad 12
  __shared__ float sTabT[8][156];                 // rpe transposed [h][idx]
  __shared__ int sRel[1024];
  __shared__ float sMask[32][33];                 // pad 1

  const size_t qbase = (size_t)w * (32*768);
  {
    #pragma unroll
    for (int t = 0; t < 8; ++t) {          // stage Q,K rows (1024 B each)
      int i = tid + t*256;
      int tok = i >> 6;
      int cb = (i & 63) * 16;              // 0..1008
      *(u16x8*)((char*)sQK + tok*1040 + cb) =
          *(const u16x8*)((const char*)(qkv + qbase) + tok*1536 + cb);
    }
    #pragma unroll
    for (int t = 0; t < 4; ++t) {          // stage V row-major
      int i = tid + t*256;
      int tok = i >> 5, c8 = i & 31;
      *(u16x8*)&sV[tok][c8*8] = *(const u16x8*)(qkv + qbase + tok*768 + 512 + c8*8);
    }
    for (int i = tid; i < 1224; i += 256)  // transpose rpe table -> [h][idx]
      sTabT[i & 7][i >> 3] = rpe[i];
    #pragma unroll
    for (int t = 0; t < 4; ++t) {          // pack clipped RPE indices
      int i = tid + t*256;
      const int* rp = relp + ((size_t)w*1024 + i)*3;
      int r0 = rp[0], r1 = rp[1], r2 = rp[2];
      r0 = min(max(r0, -25), 25) + 25;
      r1 = min(max(r1, -25), 25) + 76;
      r2 = min(max(r2, -25), 25) + 127;
      sRel[i] = r0 | (r1 << 8) | (r2 << 16);
    }
    #pragma unroll
    for (int d = 0; d < 4; ++d) {
      int i = tid*4 + d;
      sMask[i >> 5][i & 31] = mask[(size_t)w*1024 + i];
    }
  }
  __syncthreads();

  const float scale = 0.17677669529663687f;  // 1/sqrt(32)
  #pragma unroll
  for (int e = 0; e < 2; ++e) {
    const int h = wv*2 + e;
    bf16x8 qf[2], kf[2];
    #pragma unroll
    for (int rf = 0; rf < 2; ++rf) {
      int tok = rf*16 + lo;
      qf[rf] = *(const bf16x8*)((const char*)sQK + tok*1040 + h*64 + hi*16);
      kf[rf] = *(const bf16x8*)((const char*)sQK + tok*1040 + 512 + h*64 + hi*16);
    }
    f32x4 S[2][2] = {};
    #pragma unroll
    for (int rf = 0; rf < 2; ++rf)
      #pragma unroll
      for (int cf = 0; cf < 2; ++cf)
        S[rf][cf] = mfma16(qf[rf], kf[cf], S[rf][cf]);
    // scale + RPE bias + mask
    #pragma unroll
    for (int rf = 0; rf < 2; ++rf)
      #pragma unroll
      for (int cf = 0; cf < 2; ++cf)
        #pragma unroll
        for (int r = 0; r < 4; ++r) {
          const int qq = rf*16 + hi*4 + r;
          const int kk = cf*16 + lo;
          const int pk = sRel[qq*32 + kk];
          const float bsum = sTabT[h][pk & 255] + sTabT[h][(pk >> 8) & 255]
                           + sTabT[h][(pk >> 16) & 255];
          S[rf][cf][r] = S[rf][cf][r] * scale + bsum + sMask[qq][kk];
        }
    // row softmax over (cf, lo)
    #pragma unroll
    for (int rf = 0; rf < 2; ++rf)
      #pragma unroll
      for (int r = 0; r < 4; ++r) {
        float m0 = fmaxf(S[rf][0][r], S[rf][1][r]);
        #pragma unroll
        for (int d = 1; d < 16; d <<= 1) m0 = fmaxf(m0, __shfl_xor(m0, d));
        const float p0 = __expf(S[rf][0][r] - m0);
        const float p1 = __expf(S[rf][1][r] - m0);
        float ss = p0 + p1;
        #pragma unroll
        for (int d = 1; d < 16; d <<= 1) ss += __shfl_xor(ss, d);
        const float inv = 1.f / ss;
        S[rf][0][r] = p0 * inv;
        S[rf][1][r] = p1 * inv;
      }
    // P -> LDS (A-frag layout), then PV
    #pragma unroll
    for (int rf = 0; rf < 2; ++rf)
      #pragma unroll
      for (int cf = 0; cf < 2; ++cf)
        #pragma unroll
        for (int r = 0; r < 4; ++r)
          sP[wv][rf*16 + hi*4 + r][cf*16 + lo] = f2bf(S[rf][cf][r]);
    f32x4 O[2][2] = {};
    #pragma unroll
    for (int rf = 0; rf < 2; ++rf) {
      bf16x8 pf;
      *(u16x4*)&pf       = *(const u16x4*)&sP[wv][rf*16 + lo][hi*8];
      *((u16x4*)&pf + 1) = *(const u16x4*)&sP[wv][rf*16 + lo][hi*8 + 4];
      #pragma unroll
      for (int cf = 0; cf < 2; ++cf) {
        bf16x8 vf;
        #pragma unroll
        for (int j = 0; j < 8; ++j)
          ((bf16u*)&vf)[j] = sV[hi*8 + j][h*32 + cf*16 + lo];
        O[rf][cf] = mfma16(pf, vf, O[rf][cf]);
      }
    }
    #pragma unroll
    for (int rf = 0; rf < 2; ++rf)
      #pragma unroll
      for (int cf = 0; cf < 2; ++cf)
        #pragma unroll
        for (int r = 0; r < 4; ++r) {
          const int qq = rf*16 + hi*4 + r;
          outp[(size_t)(w*32 + qq)*256 + h*32 + cf*16 + lo] = f2bf(O[rf][cf][r]);
        }
  }
}

extern "C" void kernel_launch(void* const* d_in, const int* in_sizes, int n_in,
                              void* d_out, int out_size, void* d_ws, size_t ws_size,
                              hipStream_t stream) {
  const float* data   = (const float*)d_in[0];
  const float* mask   = (const float*)d_in[1];
  const int*   relp   = (const int*)d_in[2];
  const float* qkv_w  = (const float*)d_in[3];
  const float* qkv_b  = (const float*)d_in[4];
  const float* proj_w = (const float*)d_in[5];
  const float* proj_b = (const float*)d_in[6];
  const float* rpe    = (const float*)d_in[7];
  const float* ln1_g  = (const float*)d_in[8];
  const float* ln1_b  = (const float*)d_in[9];
  const float* ln2_g  = (const float*)d_in[10];
  const float* ln2_b  = (const float*)d_in[11];
  const float* fc1_w  = (const float*)d_in[12];
  const float* fc1_b  = (const float*)d_in[13];
  const float* fc2_w  = (const float*)d_in[14];
  const float* fc2_b  = (const float*)d_in[15];

  char* ws = (char*)d_ws;
  bf16u* wt_qkv  = (bf16u*)(ws);                 // 768x256
  bf16u* wt_proj = (bf16u*)(ws + 393216);        // 256x256
  bf16u* wt_fc1  = (bf16u*)(ws + 524288);        // 1024x256
  bf16u* wt_fc2  = (bf16u*)(ws + 1048576);       // 256x1024
  bf16u* xbuf    = (bf16u*)(ws + 2097152);                  // 131072x256
  bf16u* qkvbuf  = (bf16u*)(ws + 2097152 + 67108864);       // 131072x768 / x1024
  float* data2   = (float*)d_out;                // residual stream lives in d_out

  wprep_kernel<<<768, 256, 0, stream>>>(qkv_w, wt_qkv, 256, 768);
  wprep_kernel<<<256, 256, 0, stream>>>(proj_w, wt_proj, 256, 256);
  wprep_kernel<<<1024, 256, 0, stream>>>(fc1_w, wt_fc1, 256, 1024);
  wprep_kernel<<<1024, 256, 0, stream>>>(fc2_w, wt_fc2, 1024, 256);

  ln_kernel<<<32768, 256, 0, stream>>>(data, ln1_g, ln1_b, xbuf);
  gemm_kernel<0><<<6*1024, 256, 0, stream>>>(xbuf, wt_qkv, qkv_b, nullptr,
                                             qkvbuf, NTOK, 768, 256, 6);
  attn_kernel<<<NWIN, 256, 0, stream>>>(qkvbuf, mask, relp, rpe, xbuf);
  gemm_kernel<2><<<2*1024, 256, 0, stream>>>(xbuf, wt_proj, proj_b, data,
                                             data2, NTOK, 256, 256, 2);
  ln_kernel<<<32768, 256, 0, stream>>>(data2, ln2_g, ln2_b, xbuf);
  gemm_kernel<1><<<8*1024, 256, 0, stream>>>(xbuf, wt_fc1, fc1_b, nullptr,
                                             qkvbuf, NTOK, 1024, 256, 8);
  gemm_kernel<2><<<2*1024, 256, 0, stream>>>(qkvbuf, wt_fc2, fc2_b, data2,
                                             d_out, NTOK, 256, 1024, 2);
}

// Round 4
// 646.438 us; speedup vs baseline: 1.1636x; 1.0339x over previous
//
#include <hip/hip_runtime.h>

#define NWIN 4096
#define KTOK 32
#define CH 256
#define NH 8
#define NTOK (NWIN*KTOK)

typedef unsigned short bf16u;
typedef __attribute__((ext_vector_type(4))) float f32x4;
typedef __attribute__((ext_vector_type(4))) unsigned short u16x4;
typedef __attribute__((ext_vector_type(8))) unsigned short u16x8;
typedef __attribute__((ext_vector_type(8))) __bf16 bf16x8;

__device__ __forceinline__ unsigned short f2bf(float f) {
  unsigned u = __builtin_bit_cast(unsigned, f);
  u += 0x7fffu + ((u >> 16) & 1u);
  return (unsigned short)(u >> 16);
}

__device__ __forceinline__ f32x4 mfma16(bf16x8 a, bf16x8 b, f32x4 c) {
  return __builtin_amdgcn_mfma_f32_16x16x32_bf16(a, b, c, 0, 0, 0);
}

__device__ __forceinline__ void gl16(const void* g, void* l) {
  __builtin_amdgcn_global_load_lds(
      (const __attribute__((address_space(1))) unsigned int*)g,
      (__attribute__((address_space(3))) unsigned int*)l, 16, 0, 0);
}

__device__ __forceinline__ float gelu_f(float x) {
  float u = x + 0.044715f * x * x * x;
  return x * __builtin_amdgcn_rcpf(1.f + __expf(-1.5957691216057308f * u));
}

// ---- weight prep: W (K x N) f32 -> Wt (N x K) bf16 ----
__global__ __launch_bounds__(256) void wprep_kernel(const float* __restrict__ W,
                                                    bf16u* __restrict__ Wt,
                                                    int Kd, int Nd) {
  int idx = blockIdx.x * 256 + threadIdx.x;
  if (idx >= Kd * Nd) return;
  int k = idx / Nd, n = idx - k * Nd;
  Wt[n * Kd + k] = f2bf(W[idx]);
}

// ---- LayerNorm: one wave per 256-col row, f32 in -> bf16 out ----
__global__ __launch_bounds__(256) void ln_kernel(const float* __restrict__ x,
                                                 const float* __restrict__ g,
                                                 const float* __restrict__ b,
                                                 bf16u* __restrict__ y) {
  const int row = blockIdx.x * 4 + (threadIdx.x >> 6);
  const int lane = threadIdx.x & 63;
  const size_t base = (size_t)row * CH + lane * 4;
  const f32x4 v = *(const f32x4*)(x + base);
  float s = v[0] + v[1] + v[2] + v[3];
  float q = v[0]*v[0] + v[1]*v[1] + v[2]*v[2] + v[3]*v[3];
  #pragma unroll
  for (int d = 32; d; d >>= 1) { s += __shfl_xor(s, d); q += __shfl_xor(q, d); }
  const float mean = s * (1.f/256.f);
  const float rs = rsqrtf(q * (1.f/256.f) - mean*mean + 1e-5f);
  const f32x4 gv = *(const f32x4*)(g + lane*4);
  const f32x4 bv = *(const f32x4*)(b + lane*4);
  u16x4 o;
  #pragma unroll
  for (int d = 0; d < 4; ++d) o[d] = f2bf((v[d]-mean)*rs*gv[d] + bv[d]);
  *(u16x4*)(y + base) = o;
}

// ---- 128x128 MFMA GEMM: gl16 staging + LDS-bounce epilogue + XCD swizzle ----
// EPI 0: +bias -> bf16 ; EPI 1: +bias,gelu -> bf16 ; EPI 2: +bias+resid -> f32
template<int EPI>
__global__ __launch_bounds__(256, 2)
void gemm_kernel(const bf16u* __restrict__ A, const bf16u* __restrict__ Bt,
                 const float* __restrict__ bias, const float* __restrict__ resid,
                 void* __restrict__ out, int M, int N, int K, int nx) {
  __shared__ __align__(16) char lds[17408];
  const int tid = threadIdx.x;
  const int lane = tid & 63;
  const int wv = tid >> 6;
  const int lo = lane & 15, hi = lane >> 4;
  // T1 bijective XCD swizzle (nwg divisible by 8); bx fast within chunk.
  const int nwg = gridDim.x;
  const int cpx = nwg >> 3;
  const int swz = (blockIdx.x & 7) * cpx + (blockIdx.x >> 3);
  const int by = swz / nx, bx = swz - by * nx;
  const int bm = by * 128, bn = bx * 128;
  const int wm = (wv >> 1) * 64, wn = (wv & 1) * 64;
  char* As = lds;
  char* Bs = lds + 8192;

  f32x4 acc[4][4] = {};

  const int srow = tid >> 2;          // 0..63
  const int sk = (tid & 3) * 16;      // byte offset inside 64B k-row
  const size_t rstep = (size_t)64 * K * 2;  // bytes for 64 rows
  const char* gA = (const char*)(A + (size_t)(bm + srow) * K) + sk;
  const char* gB = (const char*)(Bt + (size_t)(bn + srow) * K) + sk;

  for (int k0 = 0; k0 < K; k0 += 32) {
    __syncthreads();
    const char* ga = gA + k0 * 2;
    const char* gb = gB + k0 * 2;
    gl16(ga,         As + tid*16);
    gl16(ga + rstep, As + 4096 + tid*16);
    gl16(gb,         Bs + tid*16);
    gl16(gb + rstep, Bs + 4096 + tid*16);
    __syncthreads();
    bf16x8 af[4], bfv[4];
    #pragma unroll
    for (int i = 0; i < 4; ++i) {
      af[i]  = *(const bf16x8*)(As + (wm + i*16 + lo)*64 + hi*16);
      bfv[i] = *(const bf16x8*)(Bs + (wn + i*16 + lo)*64 + hi*16);
    }
    #pragma unroll
    for (int i = 0; i < 4; ++i)
      #pragma unroll
      for (int j = 0; j < 4; ++j)
        acc[i][j] = mfma16(af[i], bfv[j], acc[i][j]);
  }

  __syncthreads();  // As/Bs reuse as per-wave epilogue bounce buffer
  // Per-wave [16][68] f32 region; D layout: row = hi*4+r, col = j*16+lo.
  float* Ls = (float*)(lds + wv * 4352);
  const int mb = bm + wm, nb = bn + wn;
  const int lrow = lane >> 3;          // 0..7
  const int lcol = (lane & 7) * 8;     // 0..56
  const f32x4 bv0 = *(const f32x4*)(bias + nb + lcol);
  const f32x4 bv1 = *(const f32x4*)(bias + nb + lcol + 4);

  #pragma unroll
  for (int i = 0; i < 4; ++i) {
    #pragma unroll
    for (int j = 0; j < 4; ++j)
      #pragma unroll
      for (int r = 0; r < 4; ++r)
        Ls[(hi*4 + r)*68 + j*16 + lo] = acc[i][j][r];
    #pragma unroll
    for (int p = 0; p < 2; ++p) {
      const int rr = p*8 + lrow;
      const int m = mb + i*16 + rr;
      f32x4 v0 = *(const f32x4*)(Ls + rr*68 + lcol);
      f32x4 v1 = *(const f32x4*)(Ls + rr*68 + lcol + 4);
      v0 += bv0; v1 += bv1;
      if constexpr (EPI == 2) {
        const float* rp = resid + (size_t)m*N + nb + lcol;
        v0 += *(const f32x4*)rp;
        v1 += *(const f32x4*)(rp + 4);
        float* op = (float*)out + (size_t)m*N + nb + lcol;
        *(f32x4*)op = v0;
        *(f32x4*)(op + 4) = v1;
      } else {
        if constexpr (EPI == 1) {
          #pragma unroll
          for (int d = 0; d < 4; ++d) { v0[d] = gelu_f(v0[d]); v1[d] = gelu_f(v1[d]); }
        }
        u16x8 o8;
        #pragma unroll
        for (int d = 0; d < 4; ++d) { o8[d] = f2bf(v0[d]); o8[4+d] = f2bf(v1[d]); }
        *(u16x8*)((bf16u*)out + (size_t)m*N + nb + lcol) = o8;
      }
    }
    if (i < 3) __builtin_amdgcn_s_waitcnt(0);  // no-op spacer; per-wave region reuse
  }
}

// ---- fused window attention: one block per window, 2 heads per wave ----
__global__ __launch_bounds__(256, 2)
void attn_kernel(const bf16u* __restrict__ qkv, const float* __restrict__ mask,
                 const int* __restrict__ relp, const float* __restrict__ rpe,
                 bf16u* __restrict__ outp) {
  const int w = blockIdx.x;
  const int tid = threadIdx.x, lane = tid & 63, wv = tid >> 6;
  const int lo = lane & 15, hi = lane >> 4;

  __shared__ __align__(16) bf16u sQK[32*520];     // [tok][q(256)|k(256)|pad]
  __shared__ __align__(16) bf16u sV[32][264];     // V rows, row-major, pad 8
  __shared__ __align__(16) bf16u sP[4][32][44];   // per-wave P, pad 12
  __shared__ float sTabT[8][156];                 // rpe transposed [h][idx]
  __shared__ int sRel[1024];
  __shared__ float sMask[32][33];                 // pad 1

  const size_t qbase = (size_t)w * (32*768);
  {
    #pragma unroll
    for (int t = 0; t < 8; ++t) {          // stage Q,K rows (1024 B each)
      int i = tid + t*256;
      int tok = i >> 6;
      int cb = (i & 63) * 16;              // 0..1008
      *(u16x8*)((char*)sQK + tok*1040 + cb) =
          *(const u16x8*)((const char*)(qkv + qbase) + tok*1536 + cb);
    }
    #pragma unroll
    for (int t = 0; t < 4; ++t) {          // stage V row-major
      int i = tid + t*256;
      int tok = i >> 5, c8 = i & 31;
      *(u16x8*)&sV[tok][c8*8] = *(const u16x8*)(qkv + qbase + tok*768 + 512 + c8*8);
    }
    for (int i = tid; i < 1224; i += 256)  // transpose rpe table -> [h][idx]
      sTabT[i & 7][i >> 3] = rpe[i];
    #pragma unroll
    for (int t = 0; t < 4; ++t) {          // pack clipped RPE indices
      int i = tid + t*256;
      const int* rp = relp + ((size_t)w*1024 + i)*3;
      int r0 = rp[0], r1 = rp[1], r2 = rp[2];
      r0 = min(max(r0, -25), 25) + 25;
      r1 = min(max(r1, -25), 25) + 76;
      r2 = min(max(r2, -25), 25) + 127;
      sRel[i] = r0 | (r1 << 8) | (r2 << 16);
    }
    #pragma unroll
    for (int d = 0; d < 4; ++d) {
      int i = tid*4 + d;
      sMask[i >> 5][i & 31] = mask[(size_t)w*1024 + i];
    }
  }
  __syncthreads();

  const float scale = 0.17677669529663687f;  // 1/sqrt(32)
  #pragma unroll
  for (int e = 0; e < 2; ++e) {
    const int h = wv*2 + e;
    bf16x8 qf[2], kf[2];
    #pragma unroll
    for (int rf = 0; rf < 2; ++rf) {
      int tok = rf*16 + lo;
      qf[rf] = *(const bf16x8*)((const char*)sQK + tok*1040 + h*64 + hi*16);
      kf[rf] = *(const bf16x8*)((const char*)sQK + tok*1040 + 512 + h*64 + hi*16);
    }
    f32x4 S[2][2] = {};
    #pragma unroll
    for (int rf = 0; rf < 2; ++rf)
      #pragma unroll
      for (int cf = 0; cf < 2; ++cf)
        S[rf][cf] = mfma16(qf[rf], kf[cf], S[rf][cf]);
    // scale + RPE bias + mask
    #pragma unroll
    for (int rf = 0; rf < 2; ++rf)
      #pragma unroll
      for (int cf = 0; cf < 2; ++cf)
        #pragma unroll
        for (int r = 0; r < 4; ++r) {
          const int qq = rf*16 + hi*4 + r;
          const int kk = cf*16 + lo;
          const int pk = sRel[qq*32 + kk];
          const float bsum = sTabT[h][pk & 255] + sTabT[h][(pk >> 8) & 255]
                           + sTabT[h][(pk >> 16) & 255];
          S[rf][cf][r] = S[rf][cf][r] * scale + bsum + sMask[qq][kk];
        }
    // row softmax over (cf, lo)
    #pragma unroll
    for (int rf = 0; rf < 2; ++rf)
      #pragma unroll
      for (int r = 0; r < 4; ++r) {
        float m0 = fmaxf(S[rf][0][r], S[rf][1][r]);
        #pragma unroll
        for (int d = 1; d < 16; d <<= 1) m0 = fmaxf(m0, __shfl_xor(m0, d));
        const float p0 = __expf(S[rf][0][r] - m0);
        const float p1 = __expf(S[rf][1][r] - m0);
        float ss = p0 + p1;
        #pragma unroll
        for (int d = 1; d < 16; d <<= 1) ss += __shfl_xor(ss, d);
        const float inv = 1.f / ss;
        S[rf][0][r] = p0 * inv;
        S[rf][1][r] = p1 * inv;
      }
    // P -> LDS (A-frag layout), then PV
    #pragma unroll
    for (int rf = 0; rf < 2; ++rf)
      #pragma unroll
      for (int cf = 0; cf < 2; ++cf)
        #pragma unroll
        for (int r = 0; r < 4; ++r)
          sP[wv][rf*16 + hi*4 + r][cf*16 + lo] = f2bf(S[rf][cf][r]);
    f32x4 O[2][2] = {};
    #pragma unroll
    for (int rf = 0; rf < 2; ++rf) {
      bf16x8 pf;
      *(u16x4*)&pf       = *(const u16x4*)&sP[wv][rf*16 + lo][hi*8];
      *((u16x4*)&pf + 1) = *(const u16x4*)&sP[wv][rf*16 + lo][hi*8 + 4];
      #pragma unroll
      for (int cf = 0; cf < 2; ++cf) {
        bf16x8 vf;
        #pragma unroll
        for (int j = 0; j < 8; ++j)
          ((bf16u*)&vf)[j] = sV[hi*8 + j][h*32 + cf*16 + lo];
        O[rf][cf] = mfma16(pf, vf, O[rf][cf]);
      }
    }
    #pragma unroll
    for (int rf = 0; rf < 2; ++rf)
      #pragma unroll
      for (int cf = 0; cf < 2; ++cf)
        #pragma unroll
        for (int r = 0; r < 4; ++r) {
          const int qq = rf*16 + hi*4 + r;
          outp[(size_t)(w*32 + qq)*256 + h*32 + cf*16 + lo] = f2bf(O[rf][cf][r]);
        }
  }
}

extern "C" void kernel_launch(void* const* d_in, const int* in_sizes, int n_in,
                              void* d_out, int out_size, void* d_ws, size_t ws_size,
                              hipStream_t stream) {
  const float* data   = (const float*)d_in[0];
  const float* mask   = (const float*)d_in[1];
  const int*   relp   = (const int*)d_in[2];
  const float* qkv_w  = (const float*)d_in[3];
  const float* qkv_b  = (const float*)d_in[4];
  const float* proj_w = (const float*)d_in[5];
  const float* proj_b = (const float*)d_in[6];
  const float* rpe    = (const float*)d_in[7];
  const float* ln1_g  = (const float*)d_in[8];
  const float* ln1_b  = (const float*)d_in[9];
  const float* ln2_g  = (const float*)d_in[10];
  const float* ln2_b  = (const float*)d_in[11];
  const float* fc1_w  = (const float*)d_in[12];
  const float* fc1_b  = (const float*)d_in[13];
  const float* fc2_w  = (const float*)d_in[14];
  const float* fc2_b  = (const float*)d_in[15];

  char* ws = (char*)d_ws;
  bf16u* wt_qkv  = (bf16u*)(ws);                 // 768x256
  bf16u* wt_proj = (bf16u*)(ws + 393216);        // 256x256
  bf16u* wt_fc1  = (bf16u*)(ws + 524288);        // 1024x256
  bf16u* wt_fc2  = (bf16u*)(ws + 1048576);       // 256x1024
  bf16u* xbuf    = (bf16u*)(ws + 2097152);                  // 131072x256
  bf16u* qkvbuf  = (bf16u*)(ws + 2097152 + 67108864);       // 131072x768 / x1024
  float* data2   = (float*)d_out;                // residual stream lives in d_out

  wprep_kernel<<<768, 256, 0, stream>>>(qkv_w, wt_qkv, 256, 768);
  wprep_kernel<<<256, 256, 0, stream>>>(proj_w, wt_proj, 256, 256);
  wprep_kernel<<<1024, 256, 0, stream>>>(fc1_w, wt_fc1, 256, 1024);
  wprep_kernel<<<1024, 256, 0, stream>>>(fc2_w, wt_fc2, 1024, 256);

  ln_kernel<<<32768, 256, 0, stream>>>(data, ln1_g, ln1_b, xbuf);
  gemm_kernel<0><<<6*1024, 256, 0, stream>>>(xbuf, wt_qkv, qkv_b, nullptr,
                                             qkvbuf, NTOK, 768, 256, 6);
  attn_kernel<<<NWIN, 256, 0, stream>>>(qkvbuf, mask, relp, rpe, xbuf);
  gemm_kernel<2><<<2*1024, 256, 0, stream>>>(xbuf, wt_proj, proj_b, data,
                                             data2, NTOK, 256, 256, 2);
  ln_kernel<<<32768, 256, 0, stream>>>(data2, ln2_g, ln2_b, xbuf);
  gemm_kernel<1><<<8*1024, 256, 0, stream>>>(xbuf, wt_fc1, fc1_b, nullptr,
                                             qkvbuf, NTOK, 1024, 256, 8);
  gemm_kernel<2><<<2*1024, 256, 0, stream>>>(qkvbuf, wt_fc2, fc2_b, data2,
                                             d_out, NTOK, 256, 1024, 2);
}

// Round 5
// 623.287 us; speedup vs baseline: 1.2068x; 1.0371x over previous
//
#include <hip/hip_runtime.h>

#define NWIN 4096
#define KTOK 32
#define CH 256
#define NH 8
#define NTOK (NWIN*KTOK)

typedef unsigned short bf16u;
typedef __attribute__((ext_vector_type(4))) float f32x4;
typedef __attribute__((ext_vector_type(4))) unsigned short u16x4;
typedef __attribute__((ext_vector_type(8))) unsigned short u16x8;
typedef __attribute__((ext_vector_type(8))) __bf16 bf16x8;

__device__ __forceinline__ unsigned short f2bf(float f) {
  unsigned u = __builtin_bit_cast(unsigned, f);
  u += 0x7fffu + ((u >> 16) & 1u);
  return (unsigned short)(u >> 16);
}

__device__ __forceinline__ f32x4 mfma16(bf16x8 a, bf16x8 b, f32x4 c) {
  return __builtin_amdgcn_mfma_f32_16x16x32_bf16(a, b, c, 0, 0, 0);
}

__device__ __forceinline__ void gl16(const void* g, void* l) {
  __builtin_amdgcn_global_load_lds(
      (const __attribute__((address_space(1))) unsigned int*)g,
      (__attribute__((address_space(3))) unsigned int*)l, 16, 0, 0);
}

__device__ __forceinline__ float gelu_f(float x) {
  float u = x + 0.044715f * x * x * x;
  return x * __builtin_amdgcn_rcpf(1.f + __expf(-1.5957691216057308f * u));
}

// ---- weight prep: W (K x N) f32 -> Wt (N x K) bf16 ----
__global__ __launch_bounds__(256) void wprep_kernel(const float* __restrict__ W,
                                                    bf16u* __restrict__ Wt,
                                                    int Kd, int Nd) {
  int idx = blockIdx.x * 256 + threadIdx.x;
  if (idx >= Kd * Nd) return;
  int k = idx / Nd, n = idx - k * Nd;
  Wt[n * Kd + k] = f2bf(W[idx]);
}

// ---- LayerNorm: one wave per 256-col row, f32 in -> bf16 out ----
__global__ __launch_bounds__(256) void ln_kernel(const float* __restrict__ x,
                                                 const float* __restrict__ g,
                                                 const float* __restrict__ b,
                                                 bf16u* __restrict__ y) {
  const int row = blockIdx.x * 4 + (threadIdx.x >> 6);
  const int lane = threadIdx.x & 63;
  const size_t base = (size_t)row * CH + lane * 4;
  const f32x4 v = *(const f32x4*)(x + base);
  float s = v[0] + v[1] + v[2] + v[3];
  float q = v[0]*v[0] + v[1]*v[1] + v[2]*v[2] + v[3]*v[3];
  #pragma unroll
  for (int d = 32; d; d >>= 1) { s += __shfl_xor(s, d); q += __shfl_xor(q, d); }
  const float mean = s * (1.f/256.f);
  const float rs = rsqrtf(q * (1.f/256.f) - mean*mean + 1e-5f);
  const f32x4 gv = *(const f32x4*)(g + lane*4);
  const f32x4 bv = *(const f32x4*)(b + lane*4);
  u16x4 o;
  #pragma unroll
  for (int d = 0; d < 4; ++d) o[d] = f2bf((v[d]-mean)*rs*gv[d] + bv[d]);
  *(u16x4*)(y + base) = o;
}

// ---- 128x128 MFMA GEMM: 2-phase gl16 pipeline + LDS-bounce epilogue ----
// EPI 0: +bias -> bf16 ; EPI 1: +bias,gelu -> bf16 ; EPI 2: +bias+resid -> f32
template<int EPI>
__global__ __launch_bounds__(256, 4)
void gemm_kernel(const bf16u* __restrict__ A, const bf16u* __restrict__ Bt,
                 const float* __restrict__ bias, const float* __restrict__ resid,
                 void* __restrict__ out, int M, int N, int K, int nx) {
  __shared__ __align__(16) char lds[32768];   // 2 x (As 8K | Bs 8K)
  const int tid = threadIdx.x;
  const int lane = tid & 63;
  const int wv = tid >> 6;
  const int lo = lane & 15, hi = lane >> 4;
  // T1 bijective XCD swizzle (nwg divisible by 8); bx fast within chunk.
  const int nwg = gridDim.x;
  const int cpx = nwg >> 3;
  const int swz = (blockIdx.x & 7) * cpx + (blockIdx.x >> 3);
  const int by = swz / nx, bx = swz - by * nx;
  const int bm = by * 128, bn = bx * 128;
  const int wm = (wv >> 1) * 64, wn = (wv & 1) * 64;

  f32x4 acc[4][4] = {};

  const int srow = tid >> 2;          // 0..63
  const int sk = (tid & 3) * 16;      // byte offset inside 64B k-row
  const size_t rstep = (size_t)64 * K * 2;  // bytes for 64 rows
  const char* gA = (const char*)(A + (size_t)(bm + srow) * K) + sk;
  const char* gB = (const char*)(Bt + (size_t)(bn + srow) * K) + sk;

  auto STAGE = [&](int b, int k0) {
    char* As = lds + b * 16384;
    char* Bs = As + 8192;
    const char* ga = gA + k0 * 2;
    const char* gb = gB + k0 * 2;
    gl16(ga,         As + tid*16);
    gl16(ga + rstep, As + 4096 + tid*16);
    gl16(gb,         Bs + tid*16);
    gl16(gb + rstep, Bs + 4096 + tid*16);
  };

  STAGE(0, 0);
  int cur = 0;
  for (int k0 = 0; ; k0 += 32) {
    const bool has_next = (k0 + 32 < K);
    if (has_next) {
      STAGE(cur ^ 1, k0 + 32);
      asm volatile("s_waitcnt vmcnt(4)" ::: "memory");   // current buf's loads done
    } else {
      asm volatile("s_waitcnt vmcnt(0)" ::: "memory");
    }
    __builtin_amdgcn_sched_barrier(0);
    __builtin_amdgcn_s_barrier();    // raw barrier: next-tile loads stay in flight
    const char* As = lds + cur * 16384;
    const char* Bs = As + 8192;
    bf16x8 af[4], bfv[4];
    #pragma unroll
    for (int i = 0; i < 4; ++i) {
      af[i]  = *(const bf16x8*)(As + (wm + i*16 + lo)*64 + hi*16);
      bfv[i] = *(const bf16x8*)(Bs + (wn + i*16 + lo)*64 + hi*16);
    }
    #pragma unroll
    for (int i = 0; i < 4; ++i)
      #pragma unroll
      for (int j = 0; j < 4; ++j)
        acc[i][j] = mfma16(af[i], bfv[j], acc[i][j]);
    if (!has_next) break;
    __builtin_amdgcn_s_barrier();    // all reads of buf done before overwrite
    cur ^= 1;
  }

  __syncthreads();  // full drain once; lds reused as per-wave epilogue bounce
  // Per-wave [16][68] f32 region; D layout: row = hi*4+r, col = j*16+lo.
  float* Ls = (float*)(lds + wv * 4352);
  const int mb = bm + wm, nb = bn + wn;
  const int lrow = lane >> 3;          // 0..7
  const int lcol = (lane & 7) * 8;     // 0..56
  const f32x4 bv0 = *(const f32x4*)(bias + nb + lcol);
  const f32x4 bv1 = *(const f32x4*)(bias + nb + lcol + 4);

  #pragma unroll
  for (int i = 0; i < 4; ++i) {
    #pragma unroll
    for (int j = 0; j < 4; ++j)
      #pragma unroll
      for (int r = 0; r < 4; ++r)
        Ls[(hi*4 + r)*68 + j*16 + lo] = acc[i][j][r];
    #pragma unroll
    for (int p = 0; p < 2; ++p) {
      const int rr = p*8 + lrow;
      const int m = mb + i*16 + rr;
      f32x4 v0 = *(const f32x4*)(Ls + rr*68 + lcol);
      f32x4 v1 = *(const f32x4*)(Ls + rr*68 + lcol + 4);
      v0 += bv0; v1 += bv1;
      if constexpr (EPI == 2) {
        const float* rp = resid + (size_t)m*N + nb + lcol;
        v0 += *(const f32x4*)rp;
        v1 += *(const f32x4*)(rp + 4);
        float* op = (float*)out + (size_t)m*N + nb + lcol;
        *(f32x4*)op = v0;
        *(f32x4*)(op + 4) = v1;
      } else {
        if constexpr (EPI == 1) {
          #pragma unroll
          for (int d = 0; d < 4; ++d) { v0[d] = gelu_f(v0[d]); v1[d] = gelu_f(v1[d]); }
        }
        u16x8 o8;
        #pragma unroll
        for (int d = 0; d < 4; ++d) { o8[d] = f2bf(v0[d]); o8[4+d] = f2bf(v1[d]); }
        *(u16x8*)((bf16u*)out + (size_t)m*N + nb + lcol) = o8;
      }
    }
  }
}

// ---- fused window attention: one block per window, 2 heads per wave ----
__global__ __launch_bounds__(256, 2)
void attn_kernel(const bf16u* __restrict__ qkv, const float* __restrict__ mask,
                 const int* __restrict__ relp, const float* __restrict__ rpe,
                 bf16u* __restrict__ outp) {
  const int w = blockIdx.x;
  const int tid = threadIdx.x, lane = tid & 63, wv = tid >> 6;
  const int lo = lane & 15, hi = lane >> 4;

  __shared__ __align__(16) bf16u sQK[32*520];     // [tok][q(256)|k(256)|pad]
  __shared__ __align__(16) bf16u sV[32][264];     // V rows, row-major, pad 8
  __shared__ __align__(16) bf16u sP[4][32][44];   // per-wave P, pad 12
  __shared__ float sTabT[8][156];                 // rpe transposed [h][idx]
  __shared__ int sRel[1024];
  __shared__ float sMask[32][33];                 // pad 1

  const size_t qbase = (size_t)w * (32*768);
  {
    #pragma unroll
    for (int t = 0; t < 8; ++t) {          // stage Q,K rows (1024 B each)
      int i = tid + t*256;
      int tok = i >> 6;
      int cb = (i & 63) * 16;              // 0..1008
      *(u16x8*)((char*)sQK + tok*1040 + cb) =
          *(const u16x8*)((const char*)(qkv + qbase) + tok*1536 + cb);
    }
    #pragma unroll
    for (int t = 0; t < 4; ++t) {          // stage V row-major
      int i = tid + t*256;
      int tok = i >> 5, c8 = i & 31;
      *(u16x8*)&sV[tok][c8*8] = *(const u16x8*)(qkv + qbase + tok*768 + 512 + c8*8);
    }
    for (int i = tid; i < 1224; i += 256)  // transpose rpe table -> [h][idx]
      sTabT[i & 7][i >> 3] = rpe[i];
    #pragma unroll
    for (int t = 0; t < 4; ++t) {          // pack clipped RPE indices
      int i = tid + t*256;
      const int* rp = relp + ((size_t)w*1024 + i)*3;
      int r0 = rp[0], r1 = rp[1], r2 = rp[2];
      r0 = min(max(r0, -25), 25) + 25;
      r1 = min(max(r1, -25), 25) + 76;
      r2 = min(max(r2, -25), 25) + 127;
      sRel[i] = r0 | (r1 << 8) | (r2 << 16);
    }
    #pragma unroll
    for (int d = 0; d < 4; ++d) {
      int i = tid*4 + d;
      sMask[i >> 5][i & 31] = mask[(size_t)w*1024 + i];
    }
  }
  __syncthreads();

  const float scale = 0.17677669529663687f;  // 1/sqrt(32)
  #pragma unroll
  for (int e = 0; e < 2; ++e) {
    const int h = wv*2 + e;
    bf16x8 qf[2], kf[2];
    #pragma unroll
    for (int rf = 0; rf < 2; ++rf) {
      int tok = rf*16 + lo;
      qf[rf] = *(const bf16x8*)((const char*)sQK + tok*1040 + h*64 + hi*16);
      kf[rf] = *(const bf16x8*)((const char*)sQK + tok*1040 + 512 + h*64 + hi*16);
    }
    f32x4 S[2][2] = {};
    #pragma unroll
    for (int rf = 0; rf < 2; ++rf)
      #pragma unroll
      for (int cf = 0; cf < 2; ++cf)
        S[rf][cf] = mfma16(qf[rf], kf[cf], S[rf][cf]);
    // scale + RPE bias + mask
    #pragma unroll
    for (int rf = 0; rf < 2; ++rf)
      #pragma unroll
      for (int cf = 0; cf < 2; ++cf)
        #pragma unroll
        for (int r = 0; r < 4; ++r) {
          const int qq = rf*16 + hi*4 + r;
          const int kk = cf*16 + lo;
          const int pk = sRel[qq*32 + kk];
          const float bsum = sTabT[h][pk & 255] + sTabT[h][(pk >> 8) & 255]
                           + sTabT[h][(pk >> 16) & 255];
          S[rf][cf][r] = S[rf][cf][r] * scale + bsum + sMask[qq][kk];
        }
    // row softmax over (cf, lo)
    #pragma unroll
    for (int rf = 0; rf < 2; ++rf)
      #pragma unroll
      for (int r = 0; r < 4; ++r) {
        float m0 = fmaxf(S[rf][0][r], S[rf][1][r]);
        #pragma unroll
        for (int d = 1; d < 16; d <<= 1) m0 = fmaxf(m0, __shfl_xor(m0, d));
        const float p0 = __expf(S[rf][0][r] - m0);
        const float p1 = __expf(S[rf][1][r] - m0);
        float ss = p0 + p1;
        #pragma unroll
        for (int d = 1; d < 16; d <<= 1) ss += __shfl_xor(ss, d);
        const float inv = 1.f / ss;
        S[rf][0][r] = p0 * inv;
        S[rf][1][r] = p1 * inv;
      }
    // P -> LDS (A-frag layout), then PV
    #pragma unroll
    for (int rf = 0; rf < 2; ++rf)
      #pragma unroll
      for (int cf = 0; cf < 2; ++cf)
        #pragma unroll
        for (int r = 0; r < 4; ++r)
          sP[wv][rf*16 + hi*4 + r][cf*16 + lo] = f2bf(S[rf][cf][r]);
    f32x4 O[2][2] = {};
    #pragma unroll
    for (int rf = 0; rf < 2; ++rf) {
      bf16x8 pf;
      *(u16x4*)&pf       = *(const u16x4*)&sP[wv][rf*16 + lo][hi*8];
      *((u16x4*)&pf + 1) = *(const u16x4*)&sP[wv][rf*16 + lo][hi*8 + 4];
      #pragma unroll
      for (int cf = 0; cf < 2; ++cf) {
        bf16x8 vf;
        #pragma unroll
        for (int j = 0; j < 8; ++j)
          ((bf16u*)&vf)[j] = sV[hi*8 + j][h*32 + cf*16 + lo];
        O[rf][cf] = mfma16(pf, vf, O[rf][cf]);
      }
    }
    #pragma unroll
    for (int rf = 0; rf < 2; ++rf)
      #pragma unroll
      for (int cf = 0; cf < 2; ++cf)
        #pragma unroll
        for (int r = 0; r < 4; ++r) {
          const int qq = rf*16 + hi*4 + r;
          outp[(size_t)(w*32 + qq)*256 + h*32 + cf*16 + lo] = f2bf(O[rf][cf][r]);
        }
  }
}

extern "C" void kernel_launch(void* const* d_in, const int* in_sizes, int n_in,
                              void* d_out, int out_size, void* d_ws, size_t ws_size,
                              hipStream_t stream) {
  const float* data   = (const float*)d_in[0];
  const float* mask   = (const float*)d_in[1];
  const int*   relp   = (const int*)d_in[2];
  const float* qkv_w  = (const float*)d_in[3];
  const float* qkv_b  = (const float*)d_in[4];
  const float* proj_w = (const float*)d_in[5];
  const float* proj_b = (const float*)d_in[6];
  const float* rpe    = (const float*)d_in[7];
  const float* ln1_g  = (const float*)d_in[8];
  const float* ln1_b  = (const float*)d_in[9];
  const float* ln2_g  = (const float*)d_in[10];
  const float* ln2_b  = (const float*)d_in[11];
  const float* fc1_w  = (const float*)d_in[12];
  const float* fc1_b  = (const float*)d_in[13];
  const float* fc2_w  = (const float*)d_in[14];
  const float* fc2_b  = (const float*)d_in[15];

  char* ws = (char*)d_ws;
  bf16u* wt_qkv  = (bf16u*)(ws);                 // 768x256
  bf16u* wt_proj = (bf16u*)(ws + 393216);        // 256x256
  bf16u* wt_fc1  = (bf16u*)(ws + 524288);        // 1024x256
  bf16u* wt_fc2  = (bf16u*)(ws + 1048576);       // 256x1024
  bf16u* xbuf    = (bf16u*)(ws + 2097152);                  // 131072x256
  bf16u* qkvbuf  = (bf16u*)(ws + 2097152 + 67108864);       // 131072x768 / x1024
  float* data2   = (float*)d_out;                // residual stream lives in d_out

  wprep_kernel<<<768, 256, 0, stream>>>(qkv_w, wt_qkv, 256, 768);
  wprep_kernel<<<256, 256, 0, stream>>>(proj_w, wt_proj, 256, 256);
  wprep_kernel<<<1024, 256, 0, stream>>>(fc1_w, wt_fc1, 256, 1024);
  wprep_kernel<<<1024, 256, 0, stream>>>(fc2_w, wt_fc2, 1024, 256);

  ln_kernel<<<32768, 256, 0, stream>>>(data, ln1_g, ln1_b, xbuf);
  gemm_kernel<0><<<6*1024, 256, 0, stream>>>(xbuf, wt_qkv, qkv_b, nullptr,
                                             qkvbuf, NTOK, 768, 256, 6);
  attn_kernel<<<NWIN, 256, 0, stream>>>(qkvbuf, mask, relp, rpe, xbuf);
  gemm_kernel<2><<<2*1024, 256, 0, stream>>>(xbuf, wt_proj, proj_b, data,
                                             data2, NTOK, 256, 256, 2);
  ln_kernel<<<32768, 256, 0, stream>>>(data2, ln2_g, ln2_b, xbuf);
  gemm_kernel<1><<<8*1024, 256, 0, stream>>>(xbuf, wt_fc1, fc1_b, nullptr,
                                             qkvbuf, NTOK, 1024, 256, 8);
  gemm_kernel<2><<<2*1024, 256, 0, stream>>>(qkvbuf, wt_fc2, fc2_b, data2,
                                             d_out, NTOK, 256, 1024, 2);
}